// Round 13
// baseline (206.589 us; speedup 1.0000x reference)
//
#include <hip/hip_runtime.h>
#include <hip/hip_bf16.h>

typedef __hip_bfloat16 bf16;
typedef float v2f __attribute__((ext_vector_type(2)));

constexpr int CB = 8;     // batch
constexpr int CT = 512;   // T
constexpr int CN = 64;    // N
constexpr int CD = 128;   // D
constexpr int CP = 96;    // PRED
constexpr int CH = 8;     // HEADS
constexpr int CDH = 16;   // head dim
constexpr int CHID = 256; // HID
constexpr int CM = 32;    // CEM freq tokens
constexpr int CG = 64;    // TEM freq tokens
constexpr float TWO_PI = 6.28318530717958647692f;

__device__ __forceinline__ float LD(const void* p, size_t i, bool f) {
  return f ? ((const float*)p)[i] : __bfloat162float(((const bf16*)p)[i]);
}
template <bool F32>
__device__ __forceinline__ float LDT(const void* p, size_t i) {
  return F32 ? ((const float*)p)[i] : __bfloat162float(((const bf16*)p)[i]);
}

__device__ __forceinline__ bool detect_f32(const void* x) {
  const unsigned int* xw = (const unsigned int*)x;
  unsigned int w = xw[threadIdx.x & 63];
  unsigned int e = (w >> 7) & 0xFF;
  unsigned long long m = __ballot(e >= 0x90 || e <= 0x60);
  return __popcll(m) > 3;
}

struct MArgs {
  const void *x, *dec_w, *dec_b, *out_w, *emb, *cWq, *cWk, *cWv, *cWo;
  const void *tWq, *tWk, *tWv, *tWo, *drw, *drb, *out_b, *wfuse;
  const void *w1, *b1, *w2, *b2, *w3, *b3;
  float *trendo, *Pbuf, *ewq, *ewk, *ewv, *wod, *owr, *owi;
  void* out;
};

// ================= kS2: k2+trend [0,128) | k3 8t/block [128,640)
// ================= | k_ow [640,704) | k0b [704,716) | wod [716] =================
// (256,4): VGPR 52 proven (no spills); grid 717 <= 1024 slots -> single scheduling round.
template <bool F32>
__device__ void k2_body(float* sm, const MArgs& a) {
  float* xbuf = sm;          // [512][5] padded
  float* rows = sm + 2560;   // [4][512]
  float* h1 = sm + 4608;     // [4][256]
  float* h2 = sm + 5632;     // [4][256]
  int r0 = blockIdx.x * 4;
  int b = r0 >> 6, n0 = r0 & 63;
  int tid = threadIdx.x;
  size_t xb = (size_t)b * CT * CN + n0;
  for (int i = tid; i < CT * 4; i += 256) {
    int t = i >> 2, q = i & 3;
    xbuf[t * 5 + q] = LDT<F32>(a.x, xb + (size_t)t * CN + q);
  }
  __syncthreads();
  {
    float w0 = LDT<F32>(a.dec_w, 0), w1 = LDT<F32>(a.dec_w, 1);
    float c0 = LDT<F32>(a.dec_b, 0), c1 = LDT<F32>(a.dec_b, 1);
    int q = tid & 3, tl = tid >> 2;
    int t0 = tl * 8;
    float s17 = 0.f, s49 = 0.f;
    #pragma unroll
    for (int o = -8; o <= 8; ++o) {
      int u = t0 + o; u = u < 0 ? 0 : (u > CT - 1 ? CT - 1 : u);
      s17 += xbuf[u * 5 + q];
    }
    #pragma unroll
    for (int o = -24; o <= 24; ++o) {
      int u = t0 + o; u = u < 0 ? 0 : (u > CT - 1 ? CT - 1 : u);
      s49 += xbuf[u * 5 + q];
    }
    #pragma unroll
    for (int k = 0; k < 8; ++k) {
      int t = t0 + k;
      if (k > 0) {
        int up8 = t + 8 > CT - 1 ? CT - 1 : t + 8;
        int dn9 = t - 9 < 0 ? 0 : t - 9;
        int up24 = t + 24 > CT - 1 ? CT - 1 : t + 24;
        int dn25 = t - 25 < 0 ? 0 : t - 25;
        s17 += xbuf[up8 * 5 + q] - xbuf[dn9 * 5 + q];
        s49 += xbuf[up24 * 5 + q] - xbuf[dn25 * 5 + q];
      }
      float m0 = s17 * (1.f / 17.f), m1 = s49 * (1.f / 49.f);
      float xv = xbuf[t * 5 + q];
      float l0 = xv * w0 + c0, l1 = xv * w1 + c1;
      float mx = fmaxf(l0, l1);
      float e0 = __expf(l0 - mx), e1 = __expf(l1 - mx);
      rows[q * CT + t] = (e0 * m0 + e1 * m1) / (e0 + e1);
    }
  }
  __syncthreads();
  int c = tid;
  float a0, a1, a2, a3;
  {
    float bias = LDT<F32>(a.b1, c);
    a0 = a1 = a2 = a3 = 0.f;
    #pragma unroll 16
    for (int t = 0; t < CT; ++t) {
      float w = LDT<F32>(a.w1, t * CHID + c);
      a0 += rows[0 * CT + t] * w; a1 += rows[1 * CT + t] * w;
      a2 += rows[2 * CT + t] * w; a3 += rows[3 * CT + t] * w;
    }
    h1[0 * CHID + c] = fmaxf(a0 + bias, 0.f); h1[1 * CHID + c] = fmaxf(a1 + bias, 0.f);
    h1[2 * CHID + c] = fmaxf(a2 + bias, 0.f); h1[3 * CHID + c] = fmaxf(a3 + bias, 0.f);
  }
  __syncthreads();
  {
    float bias = LDT<F32>(a.b2, c);
    a0 = a1 = a2 = a3 = 0.f;
    #pragma unroll 16
    for (int i = 0; i < CHID; ++i) {
      float w = LDT<F32>(a.w2, i * CHID + c);
      a0 += h1[0 * CHID + i] * w; a1 += h1[1 * CHID + i] * w;
      a2 += h1[2 * CHID + i] * w; a3 += h1[3 * CHID + i] * w;
    }
    h2[0 * CHID + c] = fmaxf(a0 + bias, 0.f); h2[1 * CHID + c] = fmaxf(a1 + bias, 0.f);
    h2[2 * CHID + c] = fmaxf(a2 + bias, 0.f); h2[3 * CHID + c] = fmaxf(a3 + bias, 0.f);
  }
  __syncthreads();
  if (tid < 2 * CP) {
    int p = tid < CP ? tid : tid - CP;
    int qh = tid < CP ? 0 : 2;
    float bias = LDT<F32>(a.b3, p);
    a0 = a1 = 0.f;
    #pragma unroll 16
    for (int i = 0; i < CHID; ++i) {
      float w = LDT<F32>(a.w3, i * CP + p);
      a0 += h2[qh * CHID + i] * w; a1 += h2[(qh + 1) * CHID + i] * w;
    }
    a.trendo[((size_t)(b * CN + n0 + qh)) * CP + p] = a0 + bias;
    a.trendo[((size_t)(b * CN + n0 + qh + 1)) * CP + p] = a1 + bias;
  }
}

__global__ __launch_bounds__(256, 4) void kS2(MArgs a) {
  __shared__ __align__(16) float sm[6656];
  bool f32 = detect_f32(a.x);
  int blk = blockIdx.x, tid = threadIdx.x;
  if (blk < 128) {
    if (f32) k2_body<true>(sm, a);
    else     k2_body<false>(sm, a);
  } else if (blk < 640) {
    // ---- k3: inline res + CEM collapsed attention, 8 t per block (2 per wave) ----
    float* xl = sm;              // [56][64] = 3584
    float* rowl = sm + 3584;     // [4][64]
    float* Rr = sm + 3840;       // [4][32]
    float* Ri = sm + 3968;
    float* aR = sm + 4096;
    float2* SL = (float2*)(sm + 4224); // [4][256] float2 -> floats 4224..6272
    float* prod = sm + 6272;     // [128]
    float* chl = sm + 6400;      // [8]
    float* eml = sm + 6408;      // [128]
    int bk = blk - 128;
    int b = bk >> 6, tbase = (bk & 63) * 8;
    int w = tid >> 6, lane = tid & 63;
    size_t xb = (size_t)b * CT * CN;
    // halo tile rows [tbase-24, tbase+31] clamped (56 rows)
    for (int i = tid; i < 56 * 64; i += 256) {
      int r = i >> 6, n = i & 63;
      int u = tbase - 24 + r; u = u < 0 ? 0 : (u > CT - 1 ? CT - 1 : u);
      xl[i] = LD(a.x, xb + (size_t)u * CN + n, f32);
    }
    if (tid < 128) eml[tid] = LD(a.emb, tid, f32);
    __syncthreads();
    // ch: row-coalesced partial dots; wave w -> (matrix = w>>1, d-half = w&1)
    {
      float* chp = (float*)SL; // scratch (free until softmax)
      const void* Wm = (w < 2) ? a.cWq : a.cWk;
      int d0 = (w & 1) * 64;
      float p0 = 0.f, p1 = 0.f;
      #pragma unroll 16
      for (int d = d0; d < d0 + 64; ++d) {
        float em = eml[d];
        p0 = fmaf(em, LD(Wm, (size_t)d * CD + lane, f32), p0);
        p1 = fmaf(em, LD(Wm, (size_t)d * CD + 64 + lane, f32), p1);
      }
      chp[w * 128 + lane] = p0;
      chp[w * 128 + 64 + lane] = p1;
    }
    __syncthreads();
    if (tid < 128) {
      float* chp = (float*)SL;
      float pq = chp[tid] + chp[128 + tid];
      float pk = chp[256 + tid] + chp[384 + tid];
      prod[tid] = pq * pk;
    }
    __syncthreads();
    if (tid < CH) {
      float s = 0;
      #pragma unroll
      for (int j = 0; j < 16; ++j) s += prod[tid * 16 + j];
      chl[tid] = fabsf(s);
    }
    __syncthreads(); // chl visible; chp scratch now free for SL
    for (int it = 0; it < 2; ++it) {
      int t = tbase + it * 4 + w;
      int Lt = 24 + it * 4 + w;
      // residual
      {
        float w0 = LD(a.dec_w, 0, f32), w1 = LD(a.dec_w, 1, f32);
        float c0 = LD(a.dec_b, 0, f32), c1 = LD(a.dec_b, 1, f32);
        float s17 = 0;
        #pragma unroll
        for (int o = -8; o <= 8; ++o) s17 += xl[(Lt + o) * 64 + lane];
        float s49 = 0;
        #pragma unroll
        for (int o = -24; o <= 24; ++o) s49 += xl[(Lt + o) * 64 + lane];
        float m0 = s17 * (1.f / 17.f), m1 = s49 * (1.f / 49.f);
        float xv = xl[Lt * 64 + lane];
        float l0 = xv * w0 + c0, l1 = xv * w1 + c1;
        float mx = fmaxf(l0, l1);
        float e0 = __expf(l0 - mx), e1 = __expf(l1 - mx);
        float tr = (e0 * m0 + e1 * m1) / (e0 + e1);
        rowl[w * 64 + lane] = xv - tr;
      }
      __syncthreads();
      // R-DFT over n (f = lane < 32), phasor recurrence
      if (lane < CM) {
        float cf, sf;
        sincosf((float)lane * (TWO_PI / CN), &sf, &cf);
        float wr = 1.f, wi = 0.f, rr = 0.f, ri = 0.f;
        #pragma unroll 8
        for (int n2 = 0; n2 < CN; ++n2) {
          float xv = rowl[w * 64 + n2];
          rr = fmaf(xv, wr, rr); ri = fmaf(-xv, wi, ri);
          float nr = wr * cf - wi * sf; wi = wi * cf + wr * sf; wr = nr;
        }
        Rr[w * 32 + lane] = rr; Ri[w * 32 + lane] = ri;
        aR[w * 32 + lane] = sqrtf(rr * rr + ri * ri);
      }
      __syncthreads();
      float amax = 0;
      for (int m = 0; m < CM; ++m) amax = fmaxf(amax, aR[w * 32 + m]);
      #pragma unroll
      for (int i = 0; i < 4; ++i) {
        int pair = lane + 64 * i;
        int h = pair >> 5, m = pair & 31;
        float alpha = 0.25f * chl[h] * aR[w * 32 + m];
        float den = 0, sr = 0, si = 0;
        for (int n2 = 0; n2 < CM; ++n2) {
          float e = __expf(alpha * (aR[w * 32 + n2] - amax));
          den += e; sr += e * Rr[w * 32 + n2]; si += e * Ri[w * 32 + n2];
        }
        SL[w * 256 + pair] = make_float2(sr / den, si / den);
      }
      __syncthreads();
      // irfft over f (n = lane), phasor recurrence -> P[b][n][t][h]
      {
        int n2 = lane;
        const float2* Sw = SL + w * 256;
        float acc[8];
        #pragma unroll
        for (int h = 0; h < CH; ++h) acc[h] = Sw[h * 32].x; // f=0, Re only
        float cd, sd;
        sincosf((float)n2 * (TWO_PI / CN), &sd, &cd);
        float px = cd, py = sd;
        for (int f = 1; f < CM; ++f) {
          #pragma unroll
          for (int h = 0; h < CH; ++h) {
            float2 s = Sw[h * 32 + f];
            acc[h] += 2.f * (s.x * px - s.y * py);
          }
          float nx = px * cd - py * sd; py = py * cd + px * sd; px = nx;
        }
        float* Pb = a.Pbuf + (((size_t)(b * CN + n2)) * CT + t) * CH;
        ((float4*)Pb)[0] = make_float4(acc[0] * (1.f / CN), acc[1] * (1.f / CN),
                                       acc[2] * (1.f / CN), acc[3] * (1.f / CN));
        ((float4*)Pb)[1] = make_float4(acc[4] * (1.f / CN), acc[5] * (1.f / CN),
                                       acc[6] * (1.f / CN), acc[7] * (1.f / CN));
      }
      __syncthreads();
    }
  } else if (blk < 704) {
    // ---- k_ow ----
    float* ps = sm; // [2][96][2]
    int g = blk - 640;
    int tc = tid >> 7, idx = tid & 127;
    if (idx < CP) {
      int p = idx, t0 = tc * 256;
      float s0, c0v, ss, cs;
      sincosf((float)((g * t0) & (CT - 1)) * (TWO_PI / CT), &s0, &c0v);
      sincosf((float)g * (TWO_PI / CT), &ss, &cs);
      float wr = c0v, wi = s0, ar = 0.f, ai = 0.f;
      #pragma unroll 16
      for (int t = 0; t < 256; ++t) {
        float w = LD(a.out_w, (size_t)(t0 + t) * CP + p, f32);
        ar = fmaf(w, wr, ar); ai = fmaf(w, wi, ai);
        float nr = wr * cs - wi * ss; wi = wi * cs + wr * ss; wr = nr;
      }
      ps[(tc * CP + p) * 2] = ar; ps[(tc * CP + p) * 2 + 1] = ai;
    }
    __syncthreads();
    if (tid < CP) {
      a.owr[g * CP + tid] = ps[tid * 2] + ps[(CP + tid) * 2];
      a.owi[g * CP + tid] = ps[tid * 2 + 1] + ps[(CP + tid) * 2 + 1];
    }
  } else if (blk < 716) {
    // ---- k0b self-sufficient ----
    float* eml = sm;           // [128]
    float* evl = sm + 128;     // [2][16]
    float* ewoh = sm + 160;    // [2][128]
    int bi = blk - 704;
    int half = tid >> 7, e = tid & 127;
    int pairIdx = bi * 2 + half;
    int which = pairIdx >> 3, h = pairIdx & 7;
    if (tid < 128) eml[tid] = LD(a.emb, tid, f32);
    __syncthreads();
    if (e < 16) {
      float acc = 0;
      #pragma unroll 8
      for (int d = 0; d < CD; ++d) acc += eml[d] * LD(a.cWv, d * CD + h * CDH + e, f32);
      evl[half * 16 + e] = acc;
    }
    __syncthreads();
    {
      float acc = 0;
      #pragma unroll
      for (int j = 0; j < CDH; ++j)
        acc += evl[half * 16 + j] * LD(a.cWo, (h * CDH + j) * CD + e, f32);
      ewoh[half * 128 + e] = acc;
    }
    __syncthreads();
    {
      const void* W = which == 0 ? a.tWq : (which == 1 ? a.tWk : a.tWv);
      float acc = 0;
      #pragma unroll 8
      for (int d = 0; d < CD; ++d) acc += ewoh[half * 128 + d] * LD(W, d * CD + e, f32);
      (which == 0 ? a.ewq : (which == 1 ? a.ewk : a.ewv))[h * CD + e] = acc;
    }
  } else {
    float* drl = sm;
    if (tid < 128) drl[tid] = LD(a.drw, tid, f32);
    __syncthreads();
    if (tid < 128) {
      float acc = 0;
      #pragma unroll 8
      for (int d = 0; d < CD; ++d) acc += LD(a.tWo, tid * CD + d, f32) * drl[d];
      a.wod[tid] = acc;
    }
  }
}

// ============ kC: chunked t-DFT (b128 LDS reads) + rank-8 attention + epilogue ============
__global__ __launch_bounds__(512, 4) void kC(MArgs a) {
  __shared__ __align__(16) float sm[8128];
  float* Pl = sm;                        // [64 u][68]
  float* QL = sm + 4352;                 // [64][16]
  float* Cl = sm + 5376;                 // [512]
  float* Ul = sm + 5888;                 // [64]
  float2* vdL = (float2*)(sm + 5952);    // [8][64]
  float2* zL = (float2*)(sm + 6976);     // [8][64]
  float* zrow = sm + 8000;               // [64][2]
  bool f32 = detect_f32(a.x);
  int blk = blockIdx.x, tid = threadIdx.x;
  int b = blk >> 6, n = blk & 63;
  const float4* src4 = (const float4*)(a.Pbuf + ((size_t)(b * CN + n)) * CT * CH);
  for (int i = tid; i < 1024; i += 512) {
    float4 v = src4[i];
    int t = i >> 1, half = i & 1;
    int k = t >> 6, u = t & 63;
    float* dst = Pl + u * 68 + half * 32 + k;
    dst[0] = v.x; dst[8] = v.y; dst[16] = v.z; dst[24] = v.w;
  }
  for (int id = tid; id < 512 + 64; id += 512) {
    if (id < 512) {
      int h = id >> 6, aa = (id >> 3) & 7, b2 = id & 7;
      float c = 0;
      #pragma unroll
      for (int j = 0; j < CDH; ++j)
        c += a.ewq[aa * CD + h * CDH + j] * a.ewk[b2 * CD + h * CDH + j];
      Cl[id] = c;
    } else {
      int r = id - 512;
      int h = r >> 3, aa = r & 7;
      float c = 0;
      #pragma unroll
      for (int j = 0; j < CDH; ++j) c += a.ewv[aa * CD + h * CDH + j] * a.wod[h * CDH + j];
      Ul[r] = c;
    }
  }
  __syncthreads();
  {
    int g = tid >> 3, h = tid & 7;
    float cs, sn;
    sincosf((float)g * (TWO_PI / CT), &sn, &cs);
    float wr = 1.f, wi = 0.f;
    float car[8] = {0, 0, 0, 0, 0, 0, 0, 0};
    float cai[8] = {0, 0, 0, 0, 0, 0, 0, 0};
    #pragma unroll 4
    for (int u = 0; u < 64; ++u) {
      const float4* pu = (const float4*)(Pl + u * 68 + h * 8);
      float4 lo = pu[0], hi = pu[1];
      car[0] = fmaf(lo.x, wr, car[0]); cai[0] = fmaf(lo.x, wi, cai[0]);
      car[1] = fmaf(lo.y, wr, car[1]); cai[1] = fmaf(lo.y, wi, cai[1]);
      car[2] = fmaf(lo.z, wr, car[2]); cai[2] = fmaf(lo.z, wi, cai[2]);
      car[3] = fmaf(lo.w, wr, car[3]); cai[3] = fmaf(lo.w, wi, cai[3]);
      car[4] = fmaf(hi.x, wr, car[4]); cai[4] = fmaf(hi.x, wi, cai[4]);
      car[5] = fmaf(hi.y, wr, car[5]); cai[5] = fmaf(hi.y, wi, cai[5]);
      car[6] = fmaf(hi.z, wr, car[6]); cai[6] = fmaf(hi.z, wi, cai[6]);
      car[7] = fmaf(hi.w, wr, car[7]); cai[7] = fmaf(hi.w, wi, cai[7]);
      float nr = wr * cs + wi * sn; wi = wi * cs - wr * sn; wr = nr;
    }
    float cs8, sn8;
    sincosf((float)(g & 7) * (TWO_PI / 8.f), &sn8, &cs8);
    float pr = 1.f, pi = 0.f, qr = 0.f, qi = 0.f;
    #pragma unroll
    for (int k = 0; k < 8; ++k) {
      qr += car[k] * pr - cai[k] * pi;
      qi += cai[k] * pr + car[k] * pi;
      float nr2 = pr * cs8 + pi * sn8; pi = pi * cs8 - pr * sn8; pr = nr2;
    }
    QL[g * 16 + h * 2] = qr;
    QL[g * 16 + h * 2 + 1] = qi;
  }
  __syncthreads();
  int h = tid >> 6, m = tid & 63;
  v2f qp[8];
  {
    const v2f* qrow = (const v2f*)(QL + m * 16);
    #pragma unroll
    for (int j = 0; j < 8; ++j) qp[j] = qrow[j];
  }
  {
    float vr = 0, vi = 0;
    #pragma unroll
    for (int aa = 0; aa < 8; ++aa) {
      float u = Ul[h * 8 + aa];
      vr = fmaf(qp[aa].x, u, vr); vi = fmaf(qp[aa].y, u, vi);
    }
    vdL[h * 64 + m] = make_float2(vr, vi);
  }
  v2f uu[8], vv[8];
  #pragma unroll
  for (int bb = 0; bb < 8; ++bb) {
    v2f acc = {0.f, 0.f};
    #pragma unroll
    for (int aa = 0; aa < 8; ++aa) acc += qp[aa] * Cl[(h * 8 + aa) * 8 + bb];
    uu[bb] = acc;
    vv[bb] = (v2f){acc.y, -acc.x};
  }
  __syncthreads();
  float mx = -1e30f, den = 0.f, zr = 0.f, zi = 0.f;
  #pragma unroll 4
  for (int g = 0; g < CG; ++g) {
    const v2f* y = (const v2f*)(QL + g * 16);
    v2f sr2 = {0.f, 0.f}, si2 = {0.f, 0.f};
    #pragma unroll
    for (int j = 0; j < 8; ++j) {
      v2f yj = y[j];
      sr2 = uu[j] * yj + sr2;
      si2 = vv[j] * yj + si2;
    }
    float sr = sr2.x + sr2.y;
    float si = si2.x + si2.y;
    float s = 0.25f * sqrtf(sr * sr + si * si);
    if (s > mx) {
      float f = __expf(mx - s);
      den *= f; zr *= f; zi *= f; mx = s;
    }
    float e = __expf(s - mx);
    float2 vd = vdL[h * 64 + g];
    den += e; zr += e * vd.x; zi += e * vd.y;
  }
  {
    float rv = 1.f / den;
    zL[h * 64 + m] = make_float2(zr * rv, zi * rv);
  }
  __syncthreads();
  if (tid < 128) {
    int g = tid >> 1, c = tid & 1;
    float acc = 0;
    #pragma unroll
    for (int hh = 0; hh < CH; ++hh) acc += c ? zL[hh * 64 + g].y : zL[hh * 64 + g].x;
    zrow[g * 2 + c] = acc;
  }
  __syncthreads();
  if (tid < CP) {
    int p = tid;
    float acc = zrow[0] * a.owr[p] - zrow[1] * a.owi[p]; // g=0 (bin-0 imag dropped)
    #pragma unroll 8
    for (int g = 1; g < CG; ++g)
      acc += 2.f * (zrow[g * 2] * a.owr[g * CP + p] - zrow[g * 2 + 1] * a.owi[g * CP + p]);
    float xo = acc * (1.f / CT) + LD(a.drb, 0, f32) * a.owr[p] + LD(a.out_b, p, f32);
    float val = LD(a.wfuse, 0, f32) * xo
              + LD(a.wfuse, 1, f32) * a.trendo[((size_t)(b * CN + n)) * CP + p];
    size_t oidx = ((size_t)(b * CP + p)) * CN + n;
    if (f32) ((float*)a.out)[oidx] = val;
    else ((bf16*)a.out)[oidx] = __float2bfloat16(val);
  }
}

extern "C" void kernel_launch(void* const* d_in, const int* in_sizes, int n_in,
                              void* d_out, int out_size, void* d_ws, size_t ws_size,
                              hipStream_t stream) {
  float* W = (float*)d_ws;
  MArgs a;
  a.x = d_in[0];   a.emb = d_in[1];  a.dec_w = d_in[2]; a.dec_b = d_in[3];
  a.w1 = d_in[4];  a.b1 = d_in[5];   a.w2 = d_in[6];    a.b2 = d_in[7];
  a.w3 = d_in[8];  a.b3 = d_in[9];
  a.cWq = d_in[10]; a.cWk = d_in[11]; a.cWv = d_in[12]; a.cWo = d_in[13];
  a.tWq = d_in[14]; a.tWk = d_in[15]; a.tWv = d_in[16]; a.tWo = d_in[17];
  a.drw = d_in[18]; a.drb = d_in[19]; a.out_w = d_in[20]; a.out_b = d_in[21];
  a.wfuse = d_in[22];
  a.trendo = W; W += (size_t)CB * CN * CP;
  a.Pbuf = W;   W += (size_t)CB * CN * CT * CH;
  a.ewq = W;    W += CH * CD;
  a.ewk = W;    W += CH * CD;
  a.ewv = W;    W += CH * CD;
  a.wod = W;    W += CD;
  a.owr = W;    W += CG * CP;
  a.owi = W;    W += CG * CP;
  a.out = d_out;

  kS2<<<717, 256, 0, stream>>>(a);
  kC<<<512, 512, 0, stream>>>(a);
}

// Round 14
// 184.093 us; speedup vs baseline: 1.1222x; 1.1222x over previous
//
#include <hip/hip_runtime.h>
#include <hip/hip_bf16.h>

typedef __hip_bfloat16 bf16;
typedef float v2f __attribute__((ext_vector_type(2)));

constexpr int CB = 8;     // batch
constexpr int CT = 512;   // T
constexpr int CN = 64;    // N
constexpr int CD = 128;   // D
constexpr int CP = 96;    // PRED
constexpr int CH = 8;     // HEADS
constexpr int CDH = 16;   // head dim
constexpr int CHID = 256; // HID
constexpr int CM = 32;    // CEM freq tokens
constexpr int CG = 64;    // TEM freq tokens
constexpr float TWO_PI = 6.28318530717958647692f;

__device__ __forceinline__ float LD(const void* p, size_t i, bool f) {
  return f ? ((const float*)p)[i] : __bfloat162float(((const bf16*)p)[i]);
}
template <bool F32>
__device__ __forceinline__ float LDT(const void* p, size_t i) {
  return F32 ? ((const float*)p)[i] : __bfloat162float(((const bf16*)p)[i]);
}

__device__ __forceinline__ bool detect_f32(const void* x) {
  const unsigned int* xw = (const unsigned int*)x;
  unsigned int w = xw[threadIdx.x & 63];
  unsigned int e = (w >> 7) & 0xFF;
  unsigned long long m = __ballot(e >= 0x90 || e <= 0x60);
  return __popcll(m) > 3;
}

struct MArgs {
  const void *x, *dec_w, *dec_b, *out_w, *emb, *cWq, *cWk, *cWv, *cWo;
  const void *tWq, *tWk, *tWv, *tWo, *drw, *drb, *out_b, *wfuse;
  const void *w1, *b1, *w2, *b2, *w3, *b3;
  float *trendo, *Pbuf, *ewq, *ewk, *ewv, *wod, *owr, *owi;
  void* out;
};

// ================= kS2 (round-11 proven, 59 us / VGPR 52): k2+trend [0,128) |
// ================= k3+res+ch [128,1152) | k_ow [1152,1216) | k0b [1216,1228) | wod =====
template <bool F32>
__device__ void k2_body(float* sm, const MArgs& a) {
  float* xbuf = sm;          // [512][5] padded
  float* rows = sm + 2560;   // [4][512]
  float* h1 = sm + 4608;     // [4][256]
  float* h2 = sm + 5632;     // [4][256]
  int r0 = blockIdx.x * 4;
  int b = r0 >> 6, n0 = r0 & 63;
  int tid = threadIdx.x;
  size_t xb = (size_t)b * CT * CN + n0;
  for (int i = tid; i < CT * 4; i += 256) {
    int t = i >> 2, q = i & 3;
    xbuf[t * 5 + q] = LDT<F32>(a.x, xb + (size_t)t * CN + q);
  }
  __syncthreads();
  {
    float w0 = LDT<F32>(a.dec_w, 0), w1 = LDT<F32>(a.dec_w, 1);
    float c0 = LDT<F32>(a.dec_b, 0), c1 = LDT<F32>(a.dec_b, 1);
    int q = tid & 3, tl = tid >> 2;
    int t0 = tl * 8;
    float s17 = 0.f, s49 = 0.f;
    #pragma unroll
    for (int o = -8; o <= 8; ++o) {
      int u = t0 + o; u = u < 0 ? 0 : (u > CT - 1 ? CT - 1 : u);
      s17 += xbuf[u * 5 + q];
    }
    #pragma unroll
    for (int o = -24; o <= 24; ++o) {
      int u = t0 + o; u = u < 0 ? 0 : (u > CT - 1 ? CT - 1 : u);
      s49 += xbuf[u * 5 + q];
    }
    #pragma unroll
    for (int k = 0; k < 8; ++k) {
      int t = t0 + k;
      if (k > 0) {
        int up8 = t + 8 > CT - 1 ? CT - 1 : t + 8;
        int dn9 = t - 9 < 0 ? 0 : t - 9;
        int up24 = t + 24 > CT - 1 ? CT - 1 : t + 24;
        int dn25 = t - 25 < 0 ? 0 : t - 25;
        s17 += xbuf[up8 * 5 + q] - xbuf[dn9 * 5 + q];
        s49 += xbuf[up24 * 5 + q] - xbuf[dn25 * 5 + q];
      }
      float m0 = s17 * (1.f / 17.f), m1 = s49 * (1.f / 49.f);
      float xv = xbuf[t * 5 + q];
      float l0 = xv * w0 + c0, l1 = xv * w1 + c1;
      float mx = fmaxf(l0, l1);
      float e0 = __expf(l0 - mx), e1 = __expf(l1 - mx);
      rows[q * CT + t] = (e0 * m0 + e1 * m1) / (e0 + e1);
    }
  }
  __syncthreads();
  int c = tid;
  float a0, a1, a2, a3;
  {
    float bias = LDT<F32>(a.b1, c);
    a0 = a1 = a2 = a3 = 0.f;
    #pragma unroll 16
    for (int t = 0; t < CT; ++t) {
      float w = LDT<F32>(a.w1, t * CHID + c);
      a0 += rows[0 * CT + t] * w; a1 += rows[1 * CT + t] * w;
      a2 += rows[2 * CT + t] * w; a3 += rows[3 * CT + t] * w;
    }
    h1[0 * CHID + c] = fmaxf(a0 + bias, 0.f); h1[1 * CHID + c] = fmaxf(a1 + bias, 0.f);
    h1[2 * CHID + c] = fmaxf(a2 + bias, 0.f); h1[3 * CHID + c] = fmaxf(a3 + bias, 0.f);
  }
  __syncthreads();
  {
    float bias = LDT<F32>(a.b2, c);
    a0 = a1 = a2 = a3 = 0.f;
    #pragma unroll 16
    for (int i = 0; i < CHID; ++i) {
      float w = LDT<F32>(a.w2, i * CHID + c);
      a0 += h1[0 * CHID + i] * w; a1 += h1[1 * CHID + i] * w;
      a2 += h1[2 * CHID + i] * w; a3 += h1[3 * CHID + i] * w;
    }
    h2[0 * CHID + c] = fmaxf(a0 + bias, 0.f); h2[1 * CHID + c] = fmaxf(a1 + bias, 0.f);
    h2[2 * CHID + c] = fmaxf(a2 + bias, 0.f); h2[3 * CHID + c] = fmaxf(a3 + bias, 0.f);
  }
  __syncthreads();
  if (tid < 2 * CP) {
    int p = tid < CP ? tid : tid - CP;
    int qh = tid < CP ? 0 : 2;
    float bias = LDT<F32>(a.b3, p);
    a0 = a1 = 0.f;
    #pragma unroll 16
    for (int i = 0; i < CHID; ++i) {
      float w = LDT<F32>(a.w3, i * CP + p);
      a0 += h2[qh * CHID + i] * w; a1 += h2[(qh + 1) * CHID + i] * w;
    }
    a.trendo[((size_t)(b * CN + n0 + qh)) * CP + p] = a0 + bias;
    a.trendo[((size_t)(b * CN + n0 + qh + 1)) * CP + p] = a1 + bias;
  }
}

__global__ __launch_bounds__(256, 4) void kS2(MArgs a) {
  __shared__ __align__(16) float sm[6656];
  bool f32 = detect_f32(a.x);
  int blk = blockIdx.x, tid = threadIdx.x;
  if (blk < 128) {
    if (f32) k2_body<true>(sm, a);
    else     k2_body<false>(sm, a);
  } else if (blk < 1152) {
    // ---- k3: inline res + CEM collapsed attention, 4 t per block (1/wave) ----
    float* xl = sm;              // [52][64]
    float* rowl = sm + 3328;     // [4][64]
    float* Rr = sm + 3584;       // [4][32]
    float* Ri = sm + 3712;
    float* aR = sm + 3840;
    float2* SL = (float2*)(sm + 3968); // [4][256] interleaved (re,im)
    float* prod = sm + 6016;     // [128]
    float* chl = sm + 6144;      // [8]
    float* eml = sm + 6152;      // [128]
    int bk = blk - 128;
    int b = bk >> 7, tbase = (bk & 127) * 4;
    int w = tid >> 6, lane = tid & 63;
    size_t xb = (size_t)b * CT * CN;
    for (int i = tid; i < 52 * 64; i += 256) {
      int r = i >> 6, n = i & 63;
      int u = tbase - 24 + r; u = u < 0 ? 0 : (u > CT - 1 ? CT - 1 : u);
      xl[i] = LD(a.x, xb + (size_t)u * CN + n, f32);
    }
    if (tid < 128) eml[tid] = LD(a.emb, tid, f32);
    __syncthreads();
    // ch: row-coalesced partial dots; wave w -> (matrix = w>>1, d-half = w&1)
    {
      float* chp = (float*)SL;
      const void* Wm = (w < 2) ? a.cWq : a.cWk;
      int d0 = (w & 1) * 64;
      float p0 = 0.f, p1 = 0.f;
      #pragma unroll 16
      for (int d = d0; d < d0 + 64; ++d) {
        float em = eml[d];
        p0 = fmaf(em, LD(Wm, (size_t)d * CD + lane, f32), p0);
        p1 = fmaf(em, LD(Wm, (size_t)d * CD + 64 + lane, f32), p1);
      }
      chp[w * 128 + lane] = p0;
      chp[w * 128 + 64 + lane] = p1;
    }
    __syncthreads();
    if (tid < 128) {
      float* chp = (float*)SL;
      float pq = chp[tid] + chp[128 + tid];
      float pk = chp[256 + tid] + chp[384 + tid];
      prod[tid] = pq * pk;
    }
    __syncthreads();
    if (tid < CH) {
      float s = 0;
      #pragma unroll
      for (int j = 0; j < 16; ++j) s += prod[tid * 16 + j];
      chl[tid] = fabsf(s);
    }
    // inline residual for this wave's t
    {
      int Lt = 24 + w;
      float w0 = LD(a.dec_w, 0, f32), w1 = LD(a.dec_w, 1, f32);
      float c0 = LD(a.dec_b, 0, f32), c1 = LD(a.dec_b, 1, f32);
      float s17 = 0;
      #pragma unroll
      for (int o = -8; o <= 8; ++o) s17 += xl[(Lt + o) * 64 + lane];
      float s49 = 0;
      #pragma unroll
      for (int o = -24; o <= 24; ++o) s49 += xl[(Lt + o) * 64 + lane];
      float m0 = s17 * (1.f / 17.f), m1 = s49 * (1.f / 49.f);
      float xv = xl[Lt * 64 + lane];
      float l0 = xv * w0 + c0, l1 = xv * w1 + c1;
      float mx = fmaxf(l0, l1);
      float e0 = __expf(l0 - mx), e1 = __expf(l1 - mx);
      float tr = (e0 * m0 + e1 * m1) / (e0 + e1);
      rowl[w * 64 + lane] = xv - tr;
    }
    __syncthreads();
    // R-DFT over n (f = lane < 32), phasor recurrence
    if (lane < CM) {
      float cf, sf;
      sincosf((float)lane * (TWO_PI / CN), &sf, &cf);
      float wr = 1.f, wi = 0.f, rr = 0.f, ri = 0.f;
      #pragma unroll 8
      for (int n2 = 0; n2 < CN; ++n2) {
        float xv = rowl[w * 64 + n2];
        rr = fmaf(xv, wr, rr); ri = fmaf(-xv, wi, ri);
        float nr = wr * cf - wi * sf; wi = wi * cf + wr * sf; wr = nr;
      }
      Rr[w * 32 + lane] = rr; Ri[w * 32 + lane] = ri;
      aR[w * 32 + lane] = sqrtf(rr * rr + ri * ri);
    }
    __syncthreads();
    float amax = 0;
    for (int m = 0; m < CM; ++m) amax = fmaxf(amax, aR[w * 32 + m]);
    #pragma unroll
    for (int i = 0; i < 4; ++i) {
      int pair = lane + 64 * i;
      int h = pair >> 5, m = pair & 31;
      float alpha = 0.25f * chl[h] * aR[w * 32 + m];
      float den = 0, sr = 0, si = 0;
      for (int n2 = 0; n2 < CM; ++n2) {
        float e = __expf(alpha * (aR[w * 32 + n2] - amax));
        den += e; sr += e * Rr[w * 32 + n2]; si += e * Ri[w * 32 + n2];
      }
      SL[w * 256 + pair] = make_float2(sr / den, si / den);
    }
    __syncthreads();
    // irfft over f (n = lane), phasor recurrence, float2 S reads -> P[b][n][t][h]
    {
      int n2 = lane, t = tbase + w;
      const float2* Sw = SL + w * 256;
      float acc[8];
      #pragma unroll
      for (int h = 0; h < CH; ++h) acc[h] = Sw[h * 32].x; // f=0, Re only
      float cd, sd;
      sincosf((float)n2 * (TWO_PI / CN), &sd, &cd);
      float px = cd, py = sd;
      for (int f = 1; f < CM; ++f) {
        #pragma unroll
        for (int h = 0; h < CH; ++h) {
          float2 s = Sw[h * 32 + f];
          acc[h] += 2.f * (s.x * px - s.y * py);
        }
        float nx = px * cd - py * sd; py = py * cd + px * sd; px = nx;
      }
      float* Pb = a.Pbuf + (((size_t)(b * CN + n2)) * CT + t) * CH;
      ((float4*)Pb)[0] = make_float4(acc[0] * (1.f / CN), acc[1] * (1.f / CN),
                                     acc[2] * (1.f / CN), acc[3] * (1.f / CN));
      ((float4*)Pb)[1] = make_float4(acc[4] * (1.f / CN), acc[5] * (1.f / CN),
                                     acc[6] * (1.f / CN), acc[7] * (1.f / CN));
    }
  } else if (blk < 1216) {
    // ---- k_ow ----
    float* ps = sm; // [2][96][2]
    int g = blk - 1152;
    int tc = tid >> 7, idx = tid & 127;
    if (idx < CP) {
      int p = idx, t0 = tc * 256;
      float s0, c0v, ss, cs;
      sincosf((float)((g * t0) & (CT - 1)) * (TWO_PI / CT), &s0, &c0v);
      sincosf((float)g * (TWO_PI / CT), &ss, &cs);
      float wr = c0v, wi = s0, ar = 0.f, ai = 0.f;
      #pragma unroll 16
      for (int t = 0; t < 256; ++t) {
        float w = LD(a.out_w, (size_t)(t0 + t) * CP + p, f32);
        ar = fmaf(w, wr, ar); ai = fmaf(w, wi, ai);
        float nr = wr * cs - wi * ss; wi = wi * cs + wr * ss; wr = nr;
      }
      ps[(tc * CP + p) * 2] = ar; ps[(tc * CP + p) * 2 + 1] = ai;
    }
    __syncthreads();
    if (tid < CP) {
      a.owr[g * CP + tid] = ps[tid * 2] + ps[(CP + tid) * 2];
      a.owi[g * CP + tid] = ps[tid * 2 + 1] + ps[(CP + tid) * 2 + 1];
    }
  } else if (blk < 1228) {
    // ---- k0b self-sufficient ----
    float* eml = sm;           // [128]
    float* evl = sm + 128;     // [2][16]
    float* ewoh = sm + 160;    // [2][128]
    int bi = blk - 1216;
    int half = tid >> 7, e = tid & 127;
    int pairIdx = bi * 2 + half;
    int which = pairIdx >> 3, h = pairIdx & 7;
    if (tid < 128) eml[tid] = LD(a.emb, tid, f32);
    __syncthreads();
    if (e < 16) {
      float acc = 0;
      #pragma unroll 8
      for (int d = 0; d < CD; ++d) acc += eml[d] * LD(a.cWv, d * CD + h * CDH + e, f32);
      evl[half * 16 + e] = acc;
    }
    __syncthreads();
    {
      float acc = 0;
      #pragma unroll
      for (int j = 0; j < CDH; ++j)
        acc += evl[half * 16 + j] * LD(a.cWo, (h * CDH + j) * CD + e, f32);
      ewoh[half * 128 + e] = acc;
    }
    __syncthreads();
    {
      const void* W = which == 0 ? a.tWq : (which == 1 ? a.tWk : a.tWv);
      float acc = 0;
      #pragma unroll 8
      for (int d = 0; d < CD; ++d) acc += ewoh[half * 128 + d] * LD(W, d * CD + e, f32);
      (which == 0 ? a.ewq : (which == 1 ? a.ewk : a.ewv))[h * CD + e] = acc;
    }
  } else {
    float* drl = sm;
    if (tid < 128) drl[tid] = LD(a.drw, tid, f32);
    __syncthreads();
    if (tid < 128) {
      float acc = 0;
      #pragma unroll 8
      for (int d = 0; d < CD; ++d) acc += LD(a.tWo, tid * CD + d, f32) * drl[d];
      a.wod[tid] = acc;
    }
  }
}

// ============ kC (round-12 variant): chunked t-DFT with b128 LDS reads + attention ========
// Pl layout [u][h][k] stride-68: per u-step the 8 chunk reads collapse to 2 aligned
// ds_read_b128 (lanes sharing h broadcast; chunks 2-way on banks = free per m136).
__global__ __launch_bounds__(512, 4) void kC(MArgs a) {
  __shared__ __align__(16) float sm[8128];
  float* Pl = sm;                        // [64 u][68]
  float* QL = sm + 4352;                 // [64][16]
  float* Cl = sm + 5376;                 // [512]
  float* Ul = sm + 5888;                 // [64]
  float2* vdL = (float2*)(sm + 5952);    // [8][64]
  float2* zL = (float2*)(sm + 6976);     // [8][64]
  float* zrow = sm + 8000;               // [64][2]
  bool f32 = detect_f32(a.x);
  int blk = blockIdx.x, tid = threadIdx.x;
  int b = blk >> 6, n = blk & 63;
  const float4* src4 = (const float4*)(a.Pbuf + ((size_t)(b * CN + n)) * CT * CH);
  for (int i = tid; i < 1024; i += 512) {
    float4 v = src4[i];
    int t = i >> 1, half = i & 1;
    int k = t >> 6, u = t & 63;
    float* dst = Pl + u * 68 + half * 32 + k;
    dst[0] = v.x; dst[8] = v.y; dst[16] = v.z; dst[24] = v.w;
  }
  for (int id = tid; id < 512 + 64; id += 512) {
    if (id < 512) {
      int h = id >> 6, aa = (id >> 3) & 7, b2 = id & 7;
      float c = 0;
      #pragma unroll
      for (int j = 0; j < CDH; ++j)
        c += a.ewq[aa * CD + h * CDH + j] * a.ewk[b2 * CD + h * CDH + j];
      Cl[id] = c;
    } else {
      int r = id - 512;
      int h = r >> 3, aa = r & 7;
      float c = 0;
      #pragma unroll
      for (int j = 0; j < CDH; ++j) c += a.ewv[aa * CD + h * CDH + j] * a.wod[h * CDH + j];
      Ul[r] = c;
    }
  }
  __syncthreads();
  {
    int g = tid >> 3, h = tid & 7;
    float cs, sn;
    sincosf((float)g * (TWO_PI / CT), &sn, &cs);
    float wr = 1.f, wi = 0.f;
    float car[8] = {0, 0, 0, 0, 0, 0, 0, 0};
    float cai[8] = {0, 0, 0, 0, 0, 0, 0, 0};
    #pragma unroll 4
    for (int u = 0; u < 64; ++u) {
      const float4* pu = (const float4*)(Pl + u * 68 + h * 8);
      float4 lo = pu[0], hi = pu[1];
      car[0] = fmaf(lo.x, wr, car[0]); cai[0] = fmaf(lo.x, wi, cai[0]);
      car[1] = fmaf(lo.y, wr, car[1]); cai[1] = fmaf(lo.y, wi, cai[1]);
      car[2] = fmaf(lo.z, wr, car[2]); cai[2] = fmaf(lo.z, wi, cai[2]);
      car[3] = fmaf(lo.w, wr, car[3]); cai[3] = fmaf(lo.w, wi, cai[3]);
      car[4] = fmaf(hi.x, wr, car[4]); cai[4] = fmaf(hi.x, wi, cai[4]);
      car[5] = fmaf(hi.y, wr, car[5]); cai[5] = fmaf(hi.y, wi, cai[5]);
      car[6] = fmaf(hi.z, wr, car[6]); cai[6] = fmaf(hi.z, wi, cai[6]);
      car[7] = fmaf(hi.w, wr, car[7]); cai[7] = fmaf(hi.w, wi, cai[7]);
      float nr = wr * cs + wi * sn; wi = wi * cs - wr * sn; wr = nr; // *= e^{-2pi i g/512}
    }
    float cs8, sn8;
    sincosf((float)(g & 7) * (TWO_PI / 8.f), &sn8, &cs8);
    float pr = 1.f, pi = 0.f, qr = 0.f, qi = 0.f;
    #pragma unroll
    for (int k = 0; k < 8; ++k) {
      qr += car[k] * pr - cai[k] * pi;
      qi += cai[k] * pr + car[k] * pi;
      float nr2 = pr * cs8 + pi * sn8; pi = pi * cs8 - pr * sn8; pr = nr2;
    }
    QL[g * 16 + h * 2] = qr;
    QL[g * 16 + h * 2 + 1] = qi;
  }
  __syncthreads();
  int h = tid >> 6, m = tid & 63;
  v2f qp[8];
  {
    const v2f* qrow = (const v2f*)(QL + m * 16);
    #pragma unroll
    for (int j = 0; j < 8; ++j) qp[j] = qrow[j];
  }
  {
    float vr = 0, vi = 0;
    #pragma unroll
    for (int aa = 0; aa < 8; ++aa) {
      float u = Ul[h * 8 + aa];
      vr = fmaf(qp[aa].x, u, vr); vi = fmaf(qp[aa].y, u, vi);
    }
    vdL[h * 64 + m] = make_float2(vr, vi);
  }
  v2f uu[8], vv[8];
  #pragma unroll
  for (int bb = 0; bb < 8; ++bb) {
    v2f acc = {0.f, 0.f};
    #pragma unroll
    for (int aa = 0; aa < 8; ++aa) acc += qp[aa] * Cl[(h * 8 + aa) * 8 + bb];
    uu[bb] = acc;
    vv[bb] = (v2f){acc.y, -acc.x};
  }
  __syncthreads();
  float mx = -1e30f, den = 0.f, zr = 0.f, zi = 0.f;
  #pragma unroll 4
  for (int g = 0; g < CG; ++g) {
    const v2f* y = (const v2f*)(QL + g * 16);
    v2f sr2 = {0.f, 0.f}, si2 = {0.f, 0.f};
    #pragma unroll
    for (int j = 0; j < 8; ++j) {
      v2f yj = y[j];
      sr2 = uu[j] * yj + sr2;
      si2 = vv[j] * yj + si2;
    }
    float sr = sr2.x + sr2.y;
    float si = si2.x + si2.y;
    float s = 0.25f * sqrtf(sr * sr + si * si);
    if (s > mx) {
      float f = __expf(mx - s);
      den *= f; zr *= f; zi *= f; mx = s;
    }
    float e = __expf(s - mx);
    float2 vd = vdL[h * 64 + g];
    den += e; zr += e * vd.x; zi += e * vd.y;
  }
  {
    float rv = 1.f / den;
    zL[h * 64 + m] = make_float2(zr * rv, zi * rv);
  }
  __syncthreads();
  if (tid < 128) {
    int g = tid >> 1, c = tid & 1;
    float acc = 0;
    #pragma unroll
    for (int hh = 0; hh < CH; ++hh) acc += c ? zL[hh * 64 + g].y : zL[hh * 64 + g].x;
    zrow[g * 2 + c] = acc;
  }
  __syncthreads();
  if (tid < CP) {
    int p = tid;
    float acc = zrow[0] * a.owr[p] - zrow[1] * a.owi[p]; // g=0 (bin-0 imag dropped)
    #pragma unroll 8
    for (int g = 1; g < CG; ++g)
      acc += 2.f * (zrow[g * 2] * a.owr[g * CP + p] - zrow[g * 2 + 1] * a.owi[g * CP + p]);
    float xo = acc * (1.f / CT) + LD(a.drb, 0, f32) * a.owr[p] + LD(a.out_b, p, f32);
    float val = LD(a.wfuse, 0, f32) * xo
              + LD(a.wfuse, 1, f32) * a.trendo[((size_t)(b * CN + n)) * CP + p];
    size_t oidx = ((size_t)(b * CP + p)) * CN + n;
    if (f32) ((float*)a.out)[oidx] = val;
    else ((bf16*)a.out)[oidx] = __float2bfloat16(val);
  }
}

extern "C" void kernel_launch(void* const* d_in, const int* in_sizes, int n_in,
                              void* d_out, int out_size, void* d_ws, size_t ws_size,
                              hipStream_t stream) {
  float* W = (float*)d_ws;
  MArgs a;
  a.x = d_in[0];   a.emb = d_in[1];  a.dec_w = d_in[2]; a.dec_b = d_in[3];
  a.w1 = d_in[4];  a.b1 = d_in[5];   a.w2 = d_in[6];    a.b2 = d_in[7];
  a.w3 = d_in[8];  a.b3 = d_in[9];
  a.cWq = d_in[10]; a.cWk = d_in[11]; a.cWv = d_in[12]; a.cWo = d_in[13];
  a.tWq = d_in[14]; a.tWk = d_in[15]; a.tWv = d_in[16]; a.tWo = d_in[17];
  a.drw = d_in[18]; a.drb = d_in[19]; a.out_w = d_in[20]; a.out_b = d_in[21];
  a.wfuse = d_in[22];
  a.trendo = W; W += (size_t)CB * CN * CP;
  a.Pbuf = W;   W += (size_t)CB * CN * CT * CH;
  a.ewq = W;    W += CH * CD;
  a.ewk = W;    W += CH * CD;
  a.ewv = W;    W += CH * CD;
  a.wod = W;    W += CD;
  a.owr = W;    W += CG * CP;
  a.owi = W;    W += CG * CP;
  a.out = d_out;

  kS2<<<1229, 256, 0, stream>>>(a);
  kC<<<512, 512, 0, stream>>>(a);
}